// Round 9
// baseline (326.570 us; speedup 1.0000x reference)
//
#include <hip/hip_runtime.h>
#include <hip/hip_bf16.h>
#include <stdint.h>

typedef __attribute__((ext_vector_type(8))) short bf16x8;
typedef __attribute__((ext_vector_type(4))) float f32x4;
typedef __attribute__((ext_vector_type(16))) float f32x16;
typedef unsigned short u16;
typedef unsigned int u32;

#define GLL(gp, lp) __builtin_amdgcn_global_load_lds( \
    (const __attribute__((address_space(1))) void*)(gp), \
    (__attribute__((address_space(3))) void*)(lp), 16, 0, 0)

__device__ __forceinline__ u16 f2bf_rne(float v) {
    u32 u = __float_as_uint(v);
    u32 r = (u + 0x7fffu + ((u >> 16) & 1u)) >> 16;
    return (u16)r;
}

// ---------------- pack kernels ----------------

// x (2048,39,16) f32  ->  xbd [32768][40] bf16, m = b*16+d, col 39 zero-pad
__global__ void pack_x_kernel(const float* __restrict__ x, u16* __restrict__ xbd) {
    int idx = blockIdx.x * 256 + threadIdx.x;
    if (idx >= 32768 * 40) return;
    int m = idx / 40, f = idx - m * 40;
    int b = m >> 4, d = m & 15;
    float v = (f < 39) ? x[(b * 39 + f) * 16 + d] : 0.0f;
    xbd[idx] = f2bf_rne(v);
}

// W -> MFMA-fragment-packed stream Wpk[((ks*7 + nt)*64 + lane)*8 + j]
// o = nt*32 + (lane&31), k = ks*16 + (lane>>5)*8 + j, k = f*GS + g
template <int LAYER>
__global__ void pack_wfrag_kernel(const float* __restrict__ W, u16* __restrict__ Wpk) {
    constexpr int TOT = (LAYER == 0) ? 401408 : 1835008;   // ks*7*512
    int idx = blockIdx.x * 256 + threadIdx.x;
    if (idx >= TOT) return;
    int j = idx & 7;
    int lane = (idx >> 3) & 63;
    int rest = idx >> 9;
    int nt = rest % 7, ks = rest / 7;
    int o = nt * 32 + (lane & 31);
    int k = ks * 16 + ((lane >> 5) << 3) + j;
    float v = 0.0f;
    if constexpr (LAYER == 0) {
        int f = k / 40, g = k - f * 40;
        if (o < 200 && f < 39 && g < 39) v = W[(o * 39 + f) * 39 + g];
    } else {
        int f = k / 208, g = k - f * 208;
        if (o < 200 && f < 39 && g < 200) v = W[o * 7800 + f * 200 + g];
    }
    Wpk[idx] = f2bf_rne(v);
}

// ---------------- main GEMM kernel ----------------
// C[m,o] = sum_k A[m,k]*W[o,k],  A[m, f*GS+g] = xbd[m,f]*h[m,g]
// grid 256 blocks (1/CU): block = 128 rows x 224 cols. 8 waves = 2mg x 2ng x 2kg.
// 32x32x16 MFMA. B: fragment-packed W, contiguous 1KB register loads (L2), dbuf.
// NO barriers in main loop. OVERLAP levers: kg=1 waves traverse K in REVERSE
// (decorrelates wave phases on a SIMD); s_setprio(1) around MFMA clusters (T5).
template <int LAYER>
__global__ __launch_bounds__(512, 2) void cin_gemm7(
    const u16* __restrict__ Xbd,    // [32768][40] bf16
    const u16* __restrict__ Hin,    // [32768][208] bf16 (LAYER>0)
    const u16* __restrict__ Bpk,    // fragment-packed W
    const float* __restrict__ bias, // [200] f32
    u16* __restrict__ Hout,         // [32768][208] bf16 (LAYER<2)
    float* __restrict__ out)        // [2048][600] f32
{
    constexpr int KP    = (LAYER == 0) ? 1792 : 8192;
    constexpr int NITER = KP / 64;                     // 28 / 128 (even)
    constexpr u32 MAGIC = (LAYER == 0) ? 3277u : 10083u;
    constexpr int SHIFT = (LAYER == 0) ? 17 : 21;
    constexpr int GS    = (LAYER == 0) ? 40 : 208;
    constexpr int GCL   = (LAYER == 0) ? 32 : 200;     // g0 clamp (8-aligned, in staged region)
    constexpr int HROW  = (LAYER == 0) ? 40 : 216;     // LDS row stride (elems)

    __shared__ __align__(16) char smem[114688];        // X 10240 | H 55296 ; reused as red
    u16* Xl = (u16*)smem;
    u16* Hl = (u16*)(smem + 10240);

    const int bid  = blockIdx.x;
    const int m0   = bid * 128;
    const int tid  = threadIdx.x;
    const int lane = tid & 63, wid = tid >> 6;
    const int mg = wid & 1, kg = (wid >> 1) & 1, ng = wid >> 2;
    const int l31 = lane & 31, grp8 = lane >> 5;
    const int nt0 = ng * 4;
    const int NTW = ng ? 3 : 4;

    // ---- stage X via global_load_lds (10 KB linear) ----
    {
        const char* xsrc = (const char*)(Xbd + (size_t)m0 * 40);
        for (int i = wid; i < 10; i += 8)
            GLL(xsrc + i * 1024 + lane * 16, smem + i * 1024);
    }
    // ---- stage H: global -> regs -> padded LDS rows (stride 216) ----
    if constexpr (LAYER > 0) {
        const u16* hsrc = Hin + (size_t)m0 * 208;
        #pragma unroll
        for (int j = 0; j < 7; ++j) {
            int u = tid + j * 512;
            if (u < 3328) {
                int r = u / 26, q = u - r * 26;
                int4 v = *(const int4*)(hsrc + r * 208 + q * 8);
                *(int4*)(Hl + r * 216 + q * 8) = v;
            }
        }
    }

    int xrow40[2], hrow[2];
    #pragma unroll
    for (int sub = 0; sub < 2; ++sub) {
        int r = mg * 64 + sub * 32 + l31;
        xrow40[sub] = r * 40;
        hrow[sub]   = r * HROW;
    }
    const u16* Hb = (LAYER == 0) ? Xl : Hl;

    f32x16 acc[2][4];
    #pragma unroll
    for (int s = 0; s < 2; ++s)
        #pragma unroll
        for (int t = 0; t < 4; ++t)
            acc[s][t] = (f32x16){0,0,0,0,0,0,0,0,0,0,0,0,0,0,0,0};

    bf16x8 bA[2][4], bB[2][4];

// kg=1 waves traverse the K iterations in reverse order (phase decorrelation).
#define IT(i_) (kg ? (NITER - 1 - (i_)) : (i_))

#define LOADB2(it_, dst) { \
    int itv_ = IT(it_); \
    _Pragma("unroll") \
    for (int s_ = 0; s_ < 2; ++s_) { \
        int ks_ = 4 * itv_ + 2 * kg + s_; \
        _Pragma("unroll") \
        for (int t_ = 0; t_ < 4; ++t_) \
            if (t_ < NTW) \
                dst[s_][t_] = *(const bf16x8*)(Bpk + (size_t)ks_ * 3584 + (nt0 + t_) * 512 + lane * 8); \
    } }

#define COMPUTE2(it_, src) { \
    int itv_ = IT(it_); \
    _Pragma("unroll") \
    for (int s_ = 0; s_ < 2; ++s_) { \
        int ks_ = 4 * itv_ + 2 * kg + s_; \
        int k0_ = ks_ * 16 + grp8 * 8; \
        u32 f_ = ((u32)k0_ * MAGIC) >> SHIFT; \
        f_ = (f_ > 39u) ? 39u : f_; \
        int g0_ = k0_ - (int)f_ * GS; \
        g0_ = (g0_ > GCL) ? GCL : g0_; \
        bf16x8 af2_[2]; \
        _Pragma("unroll") \
        for (int sub_ = 0; sub_ < 2; ++sub_) { \
            u16 xs_ = Xl[xrow40[sub_] + (int)f_]; \
            bf16x8 hv_ = *(const bf16x8*)&Hb[hrow[sub_] + g0_]; \
            float xf_ = __uint_as_float(((u32)xs_) << 16); \
            union { bf16x8 v; u32 w[4]; } hu_, au_; \
            hu_.v = hv_; \
            _Pragma("unroll") \
            for (int j_ = 0; j_ < 4; ++j_) { \
                float lo_ = __uint_as_float(hu_.w[j_] << 16); \
                float hi_ = __uint_as_float(hu_.w[j_] & 0xffff0000u); \
                float pl_ = xf_ * lo_, ph_ = xf_ * hi_; \
                u32 pk_; \
                asm("v_cvt_pk_bf16_f32 %0, %1, %2" : "=v"(pk_) : "v"(pl_), "v"(ph_)); \
                au_.w[j_] = pk_; \
            } \
            af2_[sub_] = au_.v; \
        } \
        __builtin_amdgcn_s_setprio(1); \
        _Pragma("unroll") \
        for (int sub_ = 0; sub_ < 2; ++sub_) { \
            _Pragma("unroll") \
            for (int t_ = 0; t_ < 4; ++t_) \
                if (t_ < NTW) \
                    acc[sub_][t_] = __builtin_amdgcn_mfma_f32_32x32x16_bf16(af2_[sub_], src[s_][t_], acc[sub_][t_], 0, 0, 0); \
        } \
        __builtin_amdgcn_s_setprio(0); \
    } }

    LOADB2(0, bA);
    __syncthreads();   // X/H staged; free-run from here

    for (int it = 0; it < NITER; it += 2) {
        LOADB2(it + 1, bB);
        COMPUTE2(it, bA);
        if (it + 2 < NITER) LOADB2(it + 2, bA);
        COMPUTE2(it + 1, bB);
    }
#undef LOADB2
#undef COMPUTE2
#undef IT

    // ---- kg merge via LDS red (X/H dead) ----
    __syncthreads();
    float* red = (float*)smem;   // tile T: [T*1024 + lane*16 + r], T = (mg*2+sub)*7 + nt
    if (kg == 1) {
        #pragma unroll
        for (int sub = 0; sub < 2; ++sub)
            #pragma unroll
            for (int t = 0; t < 4; ++t)
                if (t < NTW) {
                    int T = (mg * 2 + sub) * 7 + nt0 + t;
                    float* p = red + T * 1024 + lane * 16;
                    f32x16 a = acc[sub][t];
                    *(f32x4*)(p + 0)  = (f32x4){a[0], a[1], a[2], a[3]};
                    *(f32x4*)(p + 4)  = (f32x4){a[4], a[5], a[6], a[7]};
                    *(f32x4*)(p + 8)  = (f32x4){a[8], a[9], a[10], a[11]};
                    *(f32x4*)(p + 12) = (f32x4){a[12], a[13], a[14], a[15]};
                }
    }
    __syncthreads();

    if (kg == 0) {
        #pragma unroll
        for (int sub = 0; sub < 2; ++sub) {
            int rowbase = m0 + mg * 64 + sub * 32;
            int bA0 = rowbase >> 4;
            #pragma unroll
            for (int t = 0; t < 4; ++t) {
                if (t < NTW) {
                    int T = (mg * 2 + sub) * 7 + nt0 + t;
                    const float* p = red + T * 1024 + lane * 16;
                    f32x4 o0 = *(const f32x4*)(p + 0);
                    f32x4 o1 = *(const f32x4*)(p + 4);
                    f32x4 o2 = *(const f32x4*)(p + 8);
                    f32x4 o3 = *(const f32x4*)(p + 12);
                    int oc = nt0 * 32 + t * 32 + l31;
                    float bs = (oc < 200) ? bias[oc] : 0.0f;
                    f32x16 a = acc[sub][t];
                    float hv[16];
                    #pragma unroll
                    for (int r = 0; r < 4; ++r) {
                        hv[r]      = fmaxf(a[r]      + o0[r] + bs, 0.0f);
                        hv[r + 4]  = fmaxf(a[r + 4]  + o1[r] + bs, 0.0f);
                        hv[r + 8]  = fmaxf(a[r + 8]  + o2[r] + bs, 0.0f);
                        hv[r + 12] = fmaxf(a[r + 12] + o3[r] + bs, 0.0f);
                    }
                    if constexpr (LAYER < 2) {
                        // oc in [200,208): acc==0 (B-pad zero) -> writes 0 pad cols deterministically
                        if (oc < 208) {
                            #pragma unroll
                            for (int r = 0; r < 16; ++r) {
                                int rl = (r & 3) + 8 * (r >> 2) + 4 * grp8;
                                Hout[(size_t)(rowbase + rl) * 208 + oc] = f2bf_rne(hv[r]);
                            }
                        }
                    }
                    float sA = ((hv[0] + hv[1]) + (hv[2] + hv[3])) + ((hv[4] + hv[5]) + (hv[6] + hv[7]));
                    float sB = ((hv[8] + hv[9]) + (hv[10] + hv[11])) + ((hv[12] + hv[13]) + (hv[14] + hv[15]));
                    sA += __shfl_xor(sA, 32);
                    sB += __shfl_xor(sB, 32);
                    if (lane < 32 && oc < 200) {
                        out[(size_t)bA0 * 600 + LAYER * 200 + oc] = sA;
                        out[(size_t)(bA0 + 1) * 600 + LAYER * 200 + oc] = sB;
                    }
                }
            }
        }
    }
}

// ---------------- launch ----------------
extern "C" void kernel_launch(void* const* d_in, const int* in_sizes, int n_in,
                              void* d_out, int out_size, void* d_ws, size_t ws_size,
                              hipStream_t stream) {
    const float* x  = (const float*)d_in[0];
    const float* W0 = (const float*)d_in[1];
    const float* b0 = (const float*)d_in[2];
    const float* W1 = (const float*)d_in[3];
    const float* b1 = (const float*)d_in[4];
    const float* W2 = (const float*)d_in[5];
    const float* b2 = (const float*)d_in[6];
    float* out = (float*)d_out;

    char* ws = (char*)d_ws;
    // workspace layout (16B aligned)
    u16* xbd  = (u16*)(ws);                    // 32768*40*2 = 2,621,440 (+1024 slack)
    u16* wpk0 = (u16*)(ws + 2622464);          // 401,408*2  =   802,816
    u16* wpk1 = (u16*)(ws + 3425280);          // 1,835,008*2 = 3,670,016
    u16* wpk2 = (u16*)(ws + 7095296);          // 3,670,016
    u16* h1   = (u16*)(ws + 10765312);         // 32768*208*2 = 13,631,488 (+1024 slack)
    u16* h2   = (u16*)(ws + 24397824);         // 13,631,488

    pack_x_kernel<<<5120, 256, 0, stream>>>(x, xbd);
    pack_wfrag_kernel<0><<<1568, 256, 0, stream>>>(W0, wpk0);
    pack_wfrag_kernel<1><<<7168, 256, 0, stream>>>(W1, wpk1);
    pack_wfrag_kernel<2><<<7168, 256, 0, stream>>>(W2, wpk2);

    cin_gemm7<0><<<256, 512, 0, stream>>>(xbd, xbd, wpk0, b0, h1, out);
    cin_gemm7<1><<<256, 512, 0, stream>>>(xbd, h1, wpk1, b1, h2, out);
    cin_gemm7<2><<<256, 512, 0, stream>>>(xbd, h2, wpk2, b2, (u16*)nullptr, out);
}